// Round 2
// baseline (237.488 us; speedup 1.0000x reference)
//
#include <hip/hip_runtime.h>
#include <stdint.h>

// HeAttention (relative-position attention), MI355X/gfx950.
// Round 1: fp32 I/O (per reference dtypes), bf16 MFMA compute internally.
//
// Shapes: B=1, S=512, D=512, H=8, hd=64, NE=1024.
// Outputs (fp32, concatenated in d_out): out [512*512] then attn [8*512*512].
//
// Factorization: rel_emb[i,j] = emb_table[j-i+512] (idx in [1,1023], clip never
// binds) -> project emb_table once (rkE/rqE [1024,512]) instead of the
// reference's [S*S,512] GEMMs (275 GFLOP -> ~3.2 GFLOP).
//
// scores[h,i,j] = S1[h,i,j] + T2[h,i,e] + T3[h,e,j], e = j-i+512, where
//   S1 = q_h k_h^T (fp32), T2 = q_h rkE_h^T (fp16), T3 = rqE_h k_h^T (fp16).
//
// All GEMMs are BT-form C = A*B^T (+bias): A [M,K], B [N,K] row-major,
// fp32 accumulate via mfma_f32_16x16x32_bf16; fp32 operands are converted
// to bf16 during LDS staging.

typedef __bf16 bf16_t;
typedef bf16_t bf16x8 __attribute__((ext_vector_type(8)));
typedef float f32x4 __attribute__((ext_vector_type(4)));

__device__ __forceinline__ uint16_t f2bf(float f) {
  union { float f; uint32_t i; } c; c.f = f;
  return (uint16_t)((c.i + 0x7fffu + ((c.i >> 16) & 1u)) >> 16);  // RNE
}
__device__ __forceinline__ uint32_t pack2bf(float lo, float hi) {
  return (uint32_t)f2bf(lo) | ((uint32_t)f2bf(hi) << 16);
}

#define LSTR 40  // LDS row stride (bf16 elems): 80 B, 16B-multiple, benign banking

// C = A * B^T (+ bias). Tile 64x64, 4 waves of 32x32, K-step 32.
// aF32/bF32: operand is fp32 in global (converted to bf16 at staging).
// mode 0: fp32 store C[z*zsC + i*ldc + j]            (S1, ctx, out)
// mode 1: bf16 store C[z*zsC + i*ldc + j]            (rkE, rqE)
// mode 2: bf16 head-split C[(j>>6)*32768 + i*64 + (j&63)]        (q, k)
// mode 3: bf16 head-T     C[(j>>6)*32768 + (j&63)*512 + i]       (v^T)
// mode 4: fp16 store C[z*zsC + i*ldc + j]            (T2, T3)
__global__ __launch_bounds__(256) void gemm_bt_kernel(
    const void* __restrict__ A, int lda, int zsA, int aF32,
    const void* __restrict__ B, int ldb, int zsB, int bF32,
    const float* __restrict__ bias, int hasBias,
    void* __restrict__ C, int ldc, int zsC,
    int K, int mode)
{
  __shared__ __align__(16) uint16_t As[64 * LSTR];
  __shared__ __align__(16) uint16_t Bs[64 * LSTR];

  const int z = blockIdx.z;
  const int m0 = blockIdx.y * 64, n0 = blockIdx.x * 64;
  const int t = threadIdx.x;
  const int lane = t & 63, wave = t >> 6;
  const int wi = wave & 1, wj = wave >> 1;
  const int quad = lane >> 4, l15 = lane & 15;
  const int srow = t >> 2, scol = (t & 3) * 8;

  f32x4 acc[2][2] = {};

  for (int k0 = 0; k0 < K; k0 += 32) {
    uint4 ap, bp;
    if (aF32) {
      const float* Af = (const float*)A + (size_t)z * zsA + (size_t)(m0 + srow) * lda + (k0 + scol);
      float4 x0 = *(const float4*)(Af);
      float4 x1 = *(const float4*)(Af + 4);
      ap.x = pack2bf(x0.x, x0.y); ap.y = pack2bf(x0.z, x0.w);
      ap.z = pack2bf(x1.x, x1.y); ap.w = pack2bf(x1.z, x1.w);
    } else {
      ap = *(const uint4*)((const uint16_t*)A + (size_t)z * zsA + (size_t)(m0 + srow) * lda + (k0 + scol));
    }
    if (bF32) {
      const float* Bf = (const float*)B + (size_t)z * zsB + (size_t)(n0 + srow) * ldb + (k0 + scol);
      float4 x0 = *(const float4*)(Bf);
      float4 x1 = *(const float4*)(Bf + 4);
      bp.x = pack2bf(x0.x, x0.y); bp.y = pack2bf(x0.z, x0.w);
      bp.z = pack2bf(x1.x, x1.y); bp.w = pack2bf(x1.z, x1.w);
    } else {
      bp = *(const uint4*)((const uint16_t*)B + (size_t)z * zsB + (size_t)(n0 + srow) * ldb + (k0 + scol));
    }
    *(uint4*)(&As[srow * LSTR + scol]) = ap;
    *(uint4*)(&Bs[srow * LSTR + scol]) = bp;
    __syncthreads();
    bf16x8 af[2], bfr[2];
#pragma unroll
    for (int x = 0; x < 2; x++) {
      af[x]  = *(const bf16x8*)(&As[(wi * 32 + x * 16 + l15) * LSTR + quad * 8]);
      bfr[x] = *(const bf16x8*)(&Bs[(wj * 32 + x * 16 + l15) * LSTR + quad * 8]);
    }
#pragma unroll
    for (int x = 0; x < 2; x++)
#pragma unroll
      for (int y = 0; y < 2; y++)
        acc[x][y] = __builtin_amdgcn_mfma_f32_16x16x32_bf16(af[x], bfr[y], acc[x][y], 0, 0, 0);
    __syncthreads();
  }

#pragma unroll
  for (int x = 0; x < 2; x++) {
#pragma unroll
    for (int y = 0; y < 2; y++) {
      const int j = n0 + wj * 32 + y * 16 + l15;
      const float bval = hasBias ? bias[j] : 0.0f;
      const int ib = m0 + wi * 32 + x * 16 + quad * 4;
#pragma unroll
      for (int r = 0; r < 4; r++) {
        const int i = ib + r;
        const float v = acc[x][y][r] + bval;
        if (mode == 0) {
          ((float*)C)[(size_t)z * zsC + (size_t)i * ldc + j] = v;
        } else if (mode == 4) {
          ((_Float16*)C)[(size_t)z * zsC + (size_t)i * ldc + j] = (_Float16)v;
        } else {
          size_t off;
          if (mode == 1)      off = (size_t)z * zsC + (size_t)i * ldc + j;
          else if (mode == 2) off = (size_t)(j >> 6) * 32768 + (size_t)i * 64 + (size_t)(j & 63);
          else                off = (size_t)(j >> 6) * 32768 + (size_t)(j & 63) * 512 + (size_t)i;
          ((uint16_t*)C)[off] = f2bf(v);
        }
      }
    }
  }
}

// scores(h,i,j) = S1 + T2[h,i,e] + T3[h,e,j], e = j-i+512; softmax over j
// (scale 1/8); write attn fp32. One block per (i,h) row, 256 thr x 2 j each.
__global__ __launch_bounds__(256) void softmax_rel_kernel(
    const float* __restrict__ S1, const _Float16* __restrict__ T2,
    const _Float16* __restrict__ T3, float* __restrict__ attn)
{
  const int i = blockIdx.x, h = blockIdx.y;
  const int t = threadIdx.x;
  const int lane = t & 63, wave = t >> 6;
  __shared__ float red[8];

  float s[2];
#pragma unroll
  for (int c = 0; c < 2; c++) {
    const int j = t + c * 256;
    int e = j - i + 512;
    e = min(max(e, 0), 1023);
    const float v = S1[((size_t)h * 512 + i) * 512 + j]
                  + (float)T2[((size_t)h * 512 + i) * 1024 + e]
                  + (float)T3[((size_t)h * 1024 + e) * 512 + j];
    s[c] = v * 0.125f;
  }
  float m = fmaxf(s[0], s[1]);
#pragma unroll
  for (int o = 32; o > 0; o >>= 1) m = fmaxf(m, __shfl_xor(m, o, 64));
  if (lane == 0) red[wave] = m;
  __syncthreads();
  m = fmaxf(fmaxf(red[0], red[1]), fmaxf(red[2], red[3]));

  const float p0 = __expf(s[0] - m), p1 = __expf(s[1] - m);
  float sum = p0 + p1;
#pragma unroll
  for (int o = 32; o > 0; o >>= 1) sum += __shfl_xor(sum, o, 64);
  if (lane == 0) red[4 + wave] = sum;
  __syncthreads();
  sum = (red[4] + red[5]) + (red[6] + red[7]);
  const float inv = 1.0f / sum;

  const size_t base = ((size_t)h * 512 + i) * 512;
  attn[base + t]       = p0 * inv;
  attn[base + t + 256] = p1 * inv;
}

extern "C" void kernel_launch(void* const* d_in, const int* in_sizes, int n_in,
                              void* d_out, int out_size, void* d_ws, size_t ws_size,
                              hipStream_t stream) {
  const float* X   = (const float*)d_in[0];   // [512,512]
  const float* emb = (const float*)d_in[1];   // [1024,512]
  const float* wq  = (const float*)d_in[2];
  const float* bq  = (const float*)d_in[3];
  const float* wk  = (const float*)d_in[4];
  const float* bk  = (const float*)d_in[5];
  const float* wv  = (const float*)d_in[6];
  const float* bv  = (const float*)d_in[7];
  const float* wrk = (const float*)d_in[8];
  const float* brk = (const float*)d_in[9];
  const float* wrq = (const float*)d_in[10];
  const float* brq = (const float*)d_in[11];
  const float* wo  = (const float*)d_in[12];
  const float* bo  = (const float*)d_in[13];

  // ws layout (~28.5 MB total):
  uint16_t* q   = (uint16_t*)d_ws;            // bf16 [8][512][64]
  uint16_t* k   = q   + 262144;               // bf16 [8][512][64]
  uint16_t* vT  = k   + 262144;               // bf16 [8][64][512]
  uint16_t* rkE = vT  + 262144;               // bf16 [1024][512]
  uint16_t* rqE = rkE + 524288;               // bf16 [1024][512]
  _Float16* T2  = (_Float16*)(rqE + 524288);  // fp16 [8][512][1024]
  _Float16* T3  = T2  + 4194304;              // fp16 [8][1024][512]
  float*    ctx = (float*)(T3 + 4194304);     // fp32 [512][512]
  float*    S1  = ctx + 262144;               // fp32 [8][512][512]

  float* outp = (float*)d_out;                // [512][512]
  float* attn = (float*)d_out + 262144;       // [8][512][512]

  const dim3 blk(256);

  // Projections from fp32 inputs: q,k head-split; v head-split transposed
  gemm_bt_kernel<<<dim3(8, 8, 1), blk, 0, stream>>>(X, 512, 0, 1, wq, 512, 0, 1, bq, 1, q,  0, 0, 512, 2);
  gemm_bt_kernel<<<dim3(8, 8, 1), blk, 0, stream>>>(X, 512, 0, 1, wk, 512, 0, 1, bk, 1, k,  0, 0, 512, 2);
  gemm_bt_kernel<<<dim3(8, 8, 1), blk, 0, stream>>>(X, 512, 0, 1, wv, 512, 0, 1, bv, 1, vT, 0, 0, 512, 3);
  // Relative-embedding projections (1024 distinct rows)
  gemm_bt_kernel<<<dim3(8, 16, 1), blk, 0, stream>>>(emb, 512, 0, 1, wrk, 512, 0, 1, brk, 1, rkE, 512, 0, 512, 1);
  gemm_bt_kernel<<<dim3(8, 16, 1), blk, 0, stream>>>(emb, 512, 0, 1, wrq, 512, 0, 1, brq, 1, rqE, 512, 0, 512, 1);
  // S1[h] = q_h k_h^T (fp32); T2[h] = q_h rkE_h^T (fp16); T3[h] = rqE_h k_h^T (fp16)
  gemm_bt_kernel<<<dim3(8, 8, 8),  blk, 0, stream>>>(q, 64, 32768, 0, k, 64, 32768, 0, nullptr, 0, S1, 512, 262144, 64, 0);
  gemm_bt_kernel<<<dim3(16, 8, 8), blk, 0, stream>>>(q, 64, 32768, 0, rkE, 512, 64, 0, nullptr, 0, T2, 1024, 524288, 64, 4);
  gemm_bt_kernel<<<dim3(8, 16, 8), blk, 0, stream>>>(rqE, 512, 64, 0, k, 64, 32768, 0, nullptr, 0, T3, 512, 524288, 64, 4);
  // gather + scale + softmax -> attn (fp32, directly into d_out)
  softmax_rel_kernel<<<dim3(512, 8), blk, 0, stream>>>(S1, T2, T3, attn);
  // ctx[h] = attn_h vT_h^T -> ctx[i][h*64+d] (fp32)
  gemm_bt_kernel<<<dim3(1, 8, 8), blk, 0, stream>>>(attn, 512, 262144, 1, vT, 512, 32768, 0, nullptr, 0, ctx, 512, 64, 512, 0);
  // out = ctx wo^T + bo (fp32)
  gemm_bt_kernel<<<dim3(8, 8, 1), blk, 0, stream>>>(ctx, 512, 0, 1, wo, 512, 0, 1, bo, 1, outp, 512, 0, 512, 0);
}

// Round 3
// 143.772 us; speedup vs baseline: 1.6518x; 1.6518x over previous
//
#include <hip/hip_runtime.h>
#include <stdint.h>

// HeAttention, MI355X/gfx950 — Round 3: 5 launches, fused band-scores.
// B=1, S=512, D=512, H=8, hd=64, NE=1024. fp32 I/O, bf16 MFMA internally.
//
// scores[h,i,j] = q·k^T + q·rkE[e]^T + rqE[e]·k^T, e=j-i+512 in [1,1023]
// (clip never binds). Per 64x64 (i,j) tile, e spans a 127-row band ->
// compute banded GEMMs in-block and gather diagonals from LDS.

typedef __bf16 bf16_t;
typedef bf16_t bf16x8 __attribute__((ext_vector_type(8)));
typedef float f32x4 __attribute__((ext_vector_type(4)));

__device__ __forceinline__ uint16_t f2bf(float f) {
  union { float f; uint32_t i; } c; c.f = f;
  return (uint16_t)((c.i + 0x7fffu + ((c.i >> 16) & 1u)) >> 16);  // RNE
}
__device__ __forceinline__ uint32_t pack2bf(float lo, float hi) {
  return (uint32_t)f2bf(lo) | ((uint32_t)f2bf(hi) << 16);
}
#define MFMA(a, b, c) __builtin_amdgcn_mfma_f32_16x16x32_bf16((a), (b), (c), 0, 0, 0)

#define LSTR 40   // gemm_bt LDS stride (bf16)
#define SSTR 72   // scores staging stride (bf16)

// ---------------- generic BT GEMM (ctx, out) ----------------
// C = A * B^T (+bias). Tile 64x64, 4 waves 32x32, K-step 32.
// aF32/bF32: operand fp32 in global (bf16-converted at staging). mode0: fp32 C.
__global__ __launch_bounds__(256) void gemm_bt_kernel(
    const void* __restrict__ A, int lda, int zsA, int aF32,
    const void* __restrict__ B, int ldb, int zsB, int bF32,
    const float* __restrict__ bias, int hasBias,
    float* __restrict__ C, int ldc, int zsC, int K)
{
  __shared__ __align__(16) uint16_t As[64 * LSTR];
  __shared__ __align__(16) uint16_t Bs[64 * LSTR];
  const int z = blockIdx.z;
  const int m0 = blockIdx.y * 64, n0 = blockIdx.x * 64;
  const int t = threadIdx.x, lane = t & 63, wave = t >> 6;
  const int wi = wave & 1, wj = wave >> 1;
  const int quad = lane >> 4, l15 = lane & 15;
  const int srow = t >> 2, scol = (t & 3) * 8;

  f32x4 acc[2][2] = {};
  for (int k0 = 0; k0 < K; k0 += 32) {
    uint4 ap, bp;
    if (aF32) {
      const float* Af = (const float*)A + (size_t)z * zsA + (size_t)(m0 + srow) * lda + (k0 + scol);
      float4 x0 = *(const float4*)(Af); float4 x1 = *(const float4*)(Af + 4);
      ap.x = pack2bf(x0.x, x0.y); ap.y = pack2bf(x0.z, x0.w);
      ap.z = pack2bf(x1.x, x1.y); ap.w = pack2bf(x1.z, x1.w);
    } else {
      ap = *(const uint4*)((const uint16_t*)A + (size_t)z * zsA + (size_t)(m0 + srow) * lda + (k0 + scol));
    }
    if (bF32) {
      const float* Bf = (const float*)B + (size_t)z * zsB + (size_t)(n0 + srow) * ldb + (k0 + scol);
      float4 x0 = *(const float4*)(Bf); float4 x1 = *(const float4*)(Bf + 4);
      bp.x = pack2bf(x0.x, x0.y); bp.y = pack2bf(x0.z, x0.w);
      bp.z = pack2bf(x1.x, x1.y); bp.w = pack2bf(x1.z, x1.w);
    } else {
      bp = *(const uint4*)((const uint16_t*)B + (size_t)z * zsB + (size_t)(n0 + srow) * ldb + (k0 + scol));
    }
    *(uint4*)(&As[srow * LSTR + scol]) = ap;
    *(uint4*)(&Bs[srow * LSTR + scol]) = bp;
    __syncthreads();
    bf16x8 af[2], bfr[2];
#pragma unroll
    for (int x = 0; x < 2; x++) {
      af[x]  = *(const bf16x8*)(&As[(wi * 32 + x * 16 + l15) * LSTR + quad * 8]);
      bfr[x] = *(const bf16x8*)(&Bs[(wj * 32 + x * 16 + l15) * LSTR + quad * 8]);
    }
#pragma unroll
    for (int x = 0; x < 2; x++)
#pragma unroll
      for (int y = 0; y < 2; y++)
        acc[x][y] = MFMA(af[x], bfr[y], acc[x][y]);
    __syncthreads();
  }
#pragma unroll
  for (int x = 0; x < 2; x++)
#pragma unroll
    for (int y = 0; y < 2; y++) {
      const int j = n0 + wj * 32 + y * 16 + l15;
      const float bval = hasBias ? bias[j] : 0.0f;
      const int ib = m0 + wi * 32 + x * 16 + quad * 4;
#pragma unroll
      for (int r = 0; r < 4; r++)
        C[(size_t)z * zsC + (size_t)(ib + r) * ldc + j] = acc[x][y][r] + bval;
    }
}

// ---------------- fused projections ----------------
// 448 blocks: [0,64) X*wq->q(mode2) | [64,128) X*wk->k(2) | [128,192) X*wv->vT(3)
//             [192,320) emb*wrk->rkE(1) | [320,448) emb*wrq->rqE(1)
// mode1: C[i*512+j]; mode2: C[(j>>6)*32768+i*64+(j&63)]; mode3: C[(j>>6)*32768+(j&63)*512+i]
__global__ __launch_bounds__(256) void proj_kernel(
    const float* __restrict__ X, const float* __restrict__ emb,
    const float* __restrict__ wq, const float* __restrict__ bq,
    const float* __restrict__ wk, const float* __restrict__ bk,
    const float* __restrict__ wv, const float* __restrict__ bv,
    const float* __restrict__ wrk, const float* __restrict__ brk,
    const float* __restrict__ wrq, const float* __restrict__ brq,
    uint16_t* __restrict__ q, uint16_t* __restrict__ k, uint16_t* __restrict__ vT,
    uint16_t* __restrict__ rkE, uint16_t* __restrict__ rqE)
{
  int bid = blockIdx.x;
  const float *A, *B, *bias; uint16_t* C; int mode;
  if (bid < 64)       {            A = X;   B = wq;  bias = bq;  C = q;   mode = 2; }
  else if (bid < 128) { bid -= 64; A = X;   B = wk;  bias = bk;  C = k;   mode = 2; }
  else if (bid < 192) { bid -= 128; A = X;  B = wv;  bias = bv;  C = vT;  mode = 3; }
  else if (bid < 320) { bid -= 192; A = emb; B = wrk; bias = brk; C = rkE; mode = 1; }
  else                { bid -= 320; A = emb; B = wrq; bias = brq; C = rqE; mode = 1; }
  const int m0 = (bid >> 3) * 64, n0 = (bid & 7) * 64;

  __shared__ __align__(16) uint16_t As[64 * LSTR];
  __shared__ __align__(16) uint16_t Bs[64 * LSTR];
  const int t = threadIdx.x, lane = t & 63, wave = t >> 6;
  const int wi = wave & 1, wj = wave >> 1;
  const int quad = lane >> 4, l15 = lane & 15;
  const int srow = t >> 2, scol = (t & 3) * 8;

  f32x4 acc[2][2] = {};
  for (int k0 = 0; k0 < 512; k0 += 32) {
    const float* Af = A + (size_t)(m0 + srow) * 512 + (k0 + scol);
    const float* Bf = B + (size_t)(n0 + srow) * 512 + (k0 + scol);
    float4 a0 = *(const float4*)(Af), a1 = *(const float4*)(Af + 4);
    float4 b0 = *(const float4*)(Bf), b1 = *(const float4*)(Bf + 4);
    uint4 ap, bp;
    ap.x = pack2bf(a0.x, a0.y); ap.y = pack2bf(a0.z, a0.w);
    ap.z = pack2bf(a1.x, a1.y); ap.w = pack2bf(a1.z, a1.w);
    bp.x = pack2bf(b0.x, b0.y); bp.y = pack2bf(b0.z, b0.w);
    bp.z = pack2bf(b1.x, b1.y); bp.w = pack2bf(b1.z, b1.w);
    *(uint4*)(&As[srow * LSTR + scol]) = ap;
    *(uint4*)(&Bs[srow * LSTR + scol]) = bp;
    __syncthreads();
    bf16x8 af[2], bfr[2];
#pragma unroll
    for (int x = 0; x < 2; x++) {
      af[x]  = *(const bf16x8*)(&As[(wi * 32 + x * 16 + l15) * LSTR + quad * 8]);
      bfr[x] = *(const bf16x8*)(&Bs[(wj * 32 + x * 16 + l15) * LSTR + quad * 8]);
    }
#pragma unroll
    for (int x = 0; x < 2; x++)
#pragma unroll
      for (int y = 0; y < 2; y++)
        acc[x][y] = MFMA(af[x], bfr[y], acc[x][y]);
    __syncthreads();
  }
#pragma unroll
  for (int x = 0; x < 2; x++)
#pragma unroll
    for (int y = 0; y < 2; y++) {
      const int j = n0 + wj * 32 + y * 16 + l15;
      const float bval = bias[j];
      const int ib = m0 + wi * 32 + x * 16 + quad * 4;
#pragma unroll
      for (int r = 0; r < 4; r++) {
        const int i = ib + r;
        size_t off;
        if (mode == 1)      off = (size_t)i * 512 + j;
        else if (mode == 2) off = (size_t)(j >> 6) * 32768 + (size_t)i * 64 + (size_t)(j & 63);
        else                off = (size_t)(j >> 6) * 32768 + (size_t)(j & 63) * 512 + (size_t)i;
        C[off] = f2bf(acc[x][y][r] + bval);
      }
    }
}

// ---------------- fused band scores ----------------
// Block (h, tile): 64x64 scores tile. e-band = [ebase, ebase+127), ebase=j0-i0+449.
// S1 = q_t k_t^T (64x64), U2 = q_t rkB^T (64x128), U3 = rqB k_t^T (128x64);
// S[i,j] = (S1[ii,jj] + U2[ii, jj-ii+63] + U3[jj-ii+63, jj]) * 0.125
// Band row 127 may stage garbage (e=ebase+127 can be 1024) — never read back.
__global__ __launch_bounds__(256) void scores_kernel(
    const uint16_t* __restrict__ q, const uint16_t* __restrict__ k,
    const uint16_t* __restrict__ rkE, const uint16_t* __restrict__ rqE,
    float* __restrict__ S)
{
  __shared__ __align__(16) char smem[67072];
  uint16_t* stg = (uint16_t*)smem;            // [384][SSTR]: q 0-63, k 64-127, rq 128-255, rk 256-383
  float* U2 = (float*)smem;                   // [64][130]
  float* U3 = U2 + 64 * 130;                  // [128][66]

  const int h = blockIdx.y;
  const int i0 = (blockIdx.x >> 3) * 64, j0 = (blockIdx.x & 7) * 64;
  const int ebase = j0 - i0 + 449;            // in [1, 897]
  const int t = threadIdx.x, lane = t & 63, w = t >> 6;
  const int quad = lane >> 4, l15 = lane & 15;

  for (int idx = t; idx < 3072; idx += 256) {
    const int row = idx >> 3, c = (idx & 7) * 8;
    const uint16_t* src;
    if (row < 64)       src = q   + (size_t)h * 32768 + (size_t)(i0 + row) * 64 + c;
    else if (row < 128) src = k   + (size_t)h * 32768 + (size_t)(j0 + row - 64) * 64 + c;
    else if (row < 256) src = rqE + (size_t)(ebase + row - 128) * 512 + h * 64 + c;
    else                src = rkE + (size_t)(ebase + row - 256) * 512 + h * 64 + c;
    *(uint4*)(&stg[row * SSTR + c]) = *(const uint4*)src;
  }
  __syncthreads();

  f32x4 acc1[4] = {}, acc2[8] = {}, acc3[2][4] = {};
#pragma unroll
  for (int s = 0; s < 2; s++) {
    const int ko = s * 32 + quad * 8;
    bf16x8 aq = *(const bf16x8*)(&stg[(w * 16 + l15) * SSTR + ko]);
    bf16x8 bk[4], arq[2], brk[8];
#pragma unroll
    for (int tt = 0; tt < 4; tt++) bk[tt]  = *(const bf16x8*)(&stg[(64 + tt * 16 + l15) * SSTR + ko]);
#pragma unroll
    for (int x = 0; x < 2; x++)    arq[x]  = *(const bf16x8*)(&stg[(128 + w * 32 + x * 16 + l15) * SSTR + ko]);
#pragma unroll
    for (int tt = 0; tt < 8; tt++) brk[tt] = *(const bf16x8*)(&stg[(256 + tt * 16 + l15) * SSTR + ko]);
#pragma unroll
    for (int tt = 0; tt < 4; tt++) acc1[tt] = MFMA(aq, bk[tt], acc1[tt]);
#pragma unroll
    for (int tt = 0; tt < 8; tt++) acc2[tt] = MFMA(aq, brk[tt], acc2[tt]);
#pragma unroll
    for (int x = 0; x < 2; x++)
#pragma unroll
      for (int tt = 0; tt < 4; tt++) acc3[x][tt] = MFMA(arq[x], bk[tt], acc3[x][tt]);
  }
  __syncthreads();
#pragma unroll
  for (int tt = 0; tt < 8; tt++)
#pragma unroll
    for (int r = 0; r < 4; r++)
      U2[(w * 16 + quad * 4 + r) * 130 + tt * 16 + l15] = acc2[tt][r];
#pragma unroll
  for (int x = 0; x < 2; x++)
#pragma unroll
    for (int tt = 0; tt < 4; tt++)
#pragma unroll
      for (int r = 0; r < 4; r++)
        U3[(w * 32 + x * 16 + quad * 4 + r) * 66 + tt * 16 + l15] = acc3[x][tt][r];
  __syncthreads();
#pragma unroll
  for (int tt = 0; tt < 4; tt++)
#pragma unroll
    for (int r = 0; r < 4; r++) {
      const int ii = w * 16 + quad * 4 + r, jj = tt * 16 + l15;
      const int rb = jj - ii + 63;  // [0,126]
      const float val = (acc1[tt][r] + U2[ii * 130 + rb] + U3[rb * 66 + jj]) * 0.125f;
      S[((size_t)h * 512 + i0 + ii) * 512 + j0 + jj] = val;
    }
}

// ---------------- softmax (streaming, wave-per-row) ----------------
__global__ __launch_bounds__(256) void softmax_kernel(
    const float* __restrict__ S, float* __restrict__ attn, uint16_t* __restrict__ attn_bf)
{
  const int t = threadIdx.x, lane = t & 63, w = t >> 6;
  const size_t row = (size_t)blockIdx.x * 4 + w;  // h*512+i
  const float* Sr = S + row * 512 + lane * 8;
  float4 a = *(const float4*)Sr, b = *(const float4*)(Sr + 4);
  float v[8] = {a.x, a.y, a.z, a.w, b.x, b.y, b.z, b.w};
  float m = v[0];
#pragma unroll
  for (int i = 1; i < 8; i++) m = fmaxf(m, v[i]);
#pragma unroll
  for (int o = 32; o > 0; o >>= 1) m = fmaxf(m, __shfl_xor(m, o, 64));
  float p[8], sum = 0.f;
#pragma unroll
  for (int i = 0; i < 8; i++) { p[i] = __expf(v[i] - m); sum += p[i]; }
#pragma unroll
  for (int o = 32; o > 0; o >>= 1) sum += __shfl_xor(sum, o, 64);
  const float inv = 1.0f / sum;
#pragma unroll
  for (int i = 0; i < 8; i++) p[i] *= inv;
  float* Ar = attn + row * 512 + lane * 8;
  *(float4*)Ar       = make_float4(p[0], p[1], p[2], p[3]);
  *(float4*)(Ar + 4) = make_float4(p[4], p[5], p[6], p[7]);
  uint4 pk;
  pk.x = pack2bf(p[0], p[1]); pk.y = pack2bf(p[2], p[3]);
  pk.z = pack2bf(p[4], p[5]); pk.w = pack2bf(p[6], p[7]);
  *(uint4*)(attn_bf + row * 512 + lane * 8) = pk;
}

extern "C" void kernel_launch(void* const* d_in, const int* in_sizes, int n_in,
                              void* d_out, int out_size, void* d_ws, size_t ws_size,
                              hipStream_t stream) {
  const float* X   = (const float*)d_in[0];
  const float* emb = (const float*)d_in[1];
  const float* wq  = (const float*)d_in[2];
  const float* bq  = (const float*)d_in[3];
  const float* wk  = (const float*)d_in[4];
  const float* bk  = (const float*)d_in[5];
  const float* wv  = (const float*)d_in[6];
  const float* bv  = (const float*)d_in[7];
  const float* wrk = (const float*)d_in[8];
  const float* brk = (const float*)d_in[9];
  const float* wrq = (const float*)d_in[10];
  const float* brq = (const float*)d_in[11];
  const float* wo  = (const float*)d_in[12];
  const float* bo  = (const float*)d_in[13];

  // ws layout (uint16 elems):
  uint16_t* q       = (uint16_t*)d_ws;        // [8][512][64]
  uint16_t* k       = q   + 262144;           // [8][512][64]
  uint16_t* vT      = k   + 262144;           // [8][64][512]
  uint16_t* rkE     = vT  + 262144;           // [1024][512]
  uint16_t* rqE     = rkE + 524288;           // [1024][512]
  uint16_t* attn_bf = rqE + 524288;           // [8][512][512]
  float*    S       = (float*)(attn_bf + 2097152);  // [8][512][512] fp32
  float*    ctx     = S + 2097152;            // [512][512] fp32

  float* outp = (float*)d_out;                // [512][512]
  float* attn = (float*)d_out + 262144;       // [8][512][512]

  const dim3 blk(256);
  proj_kernel<<<dim3(448), blk, 0, stream>>>(X, emb, wq, bq, wk, bk, wv, bv,
                                             wrk, brk, wrq, brq, q, k, vT, rkE, rqE);
  scores_kernel<<<dim3(64, 8), blk, 0, stream>>>(q, k, rkE, rqE, S);
  softmax_kernel<<<dim3(1024), blk, 0, stream>>>(S, attn, attn_bf);
  // ctx[h] = attn_h vT_h^T -> ctx[i][h*64+d]
  gemm_bt_kernel<<<dim3(1, 8, 8), blk, 0, stream>>>(attn_bf, 512, 262144, 0,
                                                    vT, 512, 32768, 0,
                                                    nullptr, 0, ctx, 512, 64, 512);
  // out = ctx wo^T + bo
  gemm_bt_kernel<<<dim3(8, 8, 1), blk, 0, stream>>>(ctx, 512, 0, 1,
                                                    wo, 512, 0, 1,
                                                    bo, 1, outp, 512, 0, 512);
}